// Round 1
// baseline (468.196 us; speedup 1.0000x reference)
//
#include <hip/hip_runtime.h>

typedef short bf16x8 __attribute__((ext_vector_type(8)));
typedef unsigned short u16x8 __attribute__((ext_vector_type(8)));
typedef float f32x4 __attribute__((ext_vector_type(4)));

#define BS 8
#define LQ 300
#define DIM 256
#define LV 21760

__device__ __forceinline__ unsigned short f2bf(float x) {
    unsigned u = __float_as_uint(x);
    u += 0x7fff + ((u >> 16) & 1);   // round-to-nearest-even
    return (unsigned short)(u >> 16);
}
__device__ __forceinline__ float bf2f(unsigned short s) {
    return __uint_as_float(((unsigned)s) << 16);
}

// ---------------------------------------------------------------- K1: Wt[n][k] = bf16(W_value[k][n])
__global__ void k_wt(const float* __restrict__ Wv, unsigned short* __restrict__ Wt) {
    int i = blockIdx.x * 256 + threadIdx.x;   // 65536 elements
    int n = i >> 8, k = i & 255;
    Wt[n * 256 + k] = f2bf(Wv[k * 256 + n]);
}

// ---------------------------------------------------------------- K2: v = value @ W_value + b  (M=174080,N=256,K=256)
// 128x256 tile per block, 512 threads = 8 waves (2x4), each wave 64x64 via 4x4 16x16x32 frags.
__global__ __launch_bounds__(512) void k_vproj(
    const float* __restrict__ A, const unsigned short* __restrict__ Bt,
    const float* __restrict__ bias, unsigned short* __restrict__ C)
{
    __shared__ unsigned short Alds[128][40];   // 32 k + 8 pad (16B) -> breaks bank aliasing
    const int t = threadIdx.x;
    const int lane = t & 63;
    const int wid = t >> 6;
    const int wr = wid >> 2, wc = wid & 3;
    const size_t rowBase = (size_t)blockIdx.x * 128;

    const int srow = t >> 2, skh = (t & 3) * 8;
    const float* aptr = A + (rowBase + srow) * 256 + skh;

    const int fr = lane & 15;   // row-in-frag (A) / col-in-frag (B,D)
    const int kg = lane >> 4;   // k-group (8 contiguous k per lane)

    f32x4 acc[4][4];
#pragma unroll
    for (int m = 0; m < 4; m++)
#pragma unroll
        for (int n = 0; n < 4; n++) { f32x4 z = {0.f, 0.f, 0.f, 0.f}; acc[m][n] = z; }

    for (int kk = 0; kk < 8; ++kk) {
        float4 f0 = *(const float4*)(aptr + kk * 32);
        float4 f1 = *(const float4*)(aptr + kk * 32 + 4);
        u16x8 pk;
        pk[0] = f2bf(f0.x); pk[1] = f2bf(f0.y); pk[2] = f2bf(f0.z); pk[3] = f2bf(f0.w);
        pk[4] = f2bf(f1.x); pk[5] = f2bf(f1.y); pk[6] = f2bf(f1.z); pk[7] = f2bf(f1.w);
        *(u16x8*)&Alds[srow][skh] = pk;
        __syncthreads();

        bf16x8 a[4], bb[4];
#pragma unroll
        for (int m = 0; m < 4; m++)
            a[m] = *(const bf16x8*)&Alds[wr * 64 + m * 16 + fr][kg * 8];
#pragma unroll
        for (int n = 0; n < 4; n++)
            bb[n] = *(const bf16x8*)(Bt + (size_t)(wc * 64 + n * 16 + fr) * 256 + kk * 32 + kg * 8);
#pragma unroll
        for (int m = 0; m < 4; m++)
#pragma unroll
            for (int n = 0; n < 4; n++)
                acc[m][n] = __builtin_amdgcn_mfma_f32_16x16x32_bf16(a[m], bb[n], acc[m][n], 0, 0, 0);
        __syncthreads();
    }

    // epilogue: D col = lane&15, row = (lane>>4)*4 + reg  [m89-verified layout]
#pragma unroll
    for (int m = 0; m < 4; m++) {
#pragma unroll
        for (int n = 0; n < 4; n++) {
            int col = wc * 64 + n * 16 + fr;
            float bv = bias[col];
#pragma unroll
            for (int r = 0; r < 4; r++) {
                size_t row = rowBase + wr * 64 + m * 16 + kg * 4 + r;
                C[row * 256 + col] = f2bf(acc[m][n][r] + bv);
            }
        }
    }
}

// ---------------------------------------------------------------- K3: fused offsets/attn/softmax/sample/out-proj
// One block = 4 queries of one batch. 600 blocks x 256 threads.
__global__ __launch_bounds__(256) void k_attn(
    const float* __restrict__ query, const float* __restrict__ refp,
    const float* __restrict__ W_off, const float* __restrict__ b_off,
    const float* __restrict__ W_attn, const float* __restrict__ b_attn,
    const float* __restrict__ W_out, const float* __restrict__ b_out,
    const unsigned short* __restrict__ V, float* __restrict__ out)
{
    __shared__ float qv[4][256];
    __shared__ float offs[4][256];
    __shared__ float aw[4][128];
    __shared__ float sgx[4][128], sgy[4][128];
    __shared__ float att[4][256];

    const int t = threadIdx.x;
    const int b = blockIdx.x / 75;
    const int q0 = (blockIdx.x % 75) * 4;

#pragma unroll
    for (int j = 0; j < 4; j++)
        qv[j][t] = query[((size_t)b * LQ + q0 + j) * 256 + t];
    __syncthreads();

    // sampling-offset GEMV: off[t] = q . W_off[:,t] + b_off[t]
    float ao[4];
    {
        float bo = b_off[t];
#pragma unroll
        for (int j = 0; j < 4; j++) ao[j] = bo;
    }
#pragma unroll 4
    for (int k = 0; k < 256; k++) {
        float w = W_off[k * 256 + t];
#pragma unroll
        for (int j = 0; j < 4; j++) ao[j] += qv[j][k] * w;
    }
#pragma unroll
    for (int j = 0; j < 4; j++) offs[j][t] = ao[j];

    // attention logits (threads 0..127)
    float aa[4];
    if (t < 128) {
        float ba = b_attn[t];
#pragma unroll
        for (int j = 0; j < 4; j++) aa[j] = ba;
#pragma unroll 4
        for (int k = 0; k < 256; k++) {
            float w = W_attn[k * 128 + t];
#pragma unroll
            for (int j = 0; j < 4; j++) aa[j] += qv[j][k] * w;
        }
    }
    __syncthreads();
    if (t < 128) {
#pragma unroll
        for (int j = 0; j < 4; j++) aw[j][t] = aa[j];
    }
    __syncthreads();

    // per-head softmax over L*P=16 logits (redundant within head, tiny)
    float e4[4];
    if (t < 128) {
        int hb = t & ~15;
#pragma unroll
        for (int j = 0; j < 4; j++) {
            float m = -1e30f;
            for (int i = 0; i < 16; i++) m = fmaxf(m, aw[j][hb + i]);
            float s = 0.f;
            for (int i = 0; i < 16; i++) s += __expf(aw[j][hb + i] - m);
            e4[j] = __expf(aw[j][t] - m) / s;
        }
    }
    __syncthreads();
    if (t < 128) {
#pragma unroll
        for (int j = 0; j < 4; j++) aw[j][t] = e4[j];
        // sampling locations: pt=t, l=(t>>2)&3  (pt = h*16 + l*4 + p)
        const int l = (t >> 2) & 3;
        const float Wl = (l == 0) ? 128.f : (l == 1) ? 64.f : (l == 2) ? 32.f : 16.f;
#pragma unroll
        for (int j = 0; j < 4; j++) {
            float ox = offs[j][2 * t], oy = offs[j][2 * t + 1];
            const float* rp = refp + (((size_t)b * LQ + q0 + j) * 4 + l) * 4;
            float cx = rp[0], cy = rp[1], rw = rp[2], rh = rp[3];
            float lx = cx + ox * 0.125f * rw;   // off/P * w * 0.5, P=4
            float ly = cy + oy * 0.125f * rh;
            sgx[j][t] = lx * Wl - 0.5f;         // ((2*loc-1)+1)*W/2 - 0.5
            sgy[j][t] = ly * Wl - 0.5f;         // levels are square: H==W
        }
    }
    __syncthreads();

    // gather + attention-weighted sum. thread t -> head h = t>>5, channel c = t&31; feature index = t.
    {
        const int h = t >> 5;
        float av[4];
#pragma unroll
        for (int j = 0; j < 4; j++) {
            float acc = 0.f;
#pragma unroll
            for (int jj = 0; jj < 16; jj++) {
                const int l = jj >> 2;
                const int Wl = (l == 0) ? 128 : (l == 1) ? 64 : (l == 2) ? 32 : 16;
                const int S  = (l == 0) ? 0 : (l == 1) ? 16384 : (l == 2) ? 20480 : 21504;
                int pt = h * 16 + jj;
                float a  = aw[j][pt];
                float gx = sgx[j][pt], gy = sgy[j][pt];
                float x0f = floorf(gx), y0f = floorf(gy);
                int   x0 = (int)x0f, y0 = (int)y0f;
                float wx1 = gx - x0f, wy1 = gy - y0f;
                float wx0 = 1.f - wx1, wy0 = 1.f - wy1;
                bool vx0 = (unsigned)x0 < (unsigned)Wl;
                bool vx1 = (unsigned)(x0 + 1) < (unsigned)Wl;
                bool vy0 = (unsigned)y0 < (unsigned)Wl;
                bool vy1 = (unsigned)(y0 + 1) < (unsigned)Wl;
                float v00 = 0.f, v01 = 0.f, v10 = 0.f, v11 = 0.f;
                size_t pixBase = (size_t)b * LV + S;
                if (vy0) {
                    size_t rb = (pixBase + (size_t)y0 * Wl) * 256 + t;
                    if (vx0) v00 = bf2f(V[rb + (size_t)x0 * 256]);
                    if (vx1) v01 = bf2f(V[rb + (size_t)x0 * 256 + 256]);
                }
                if (vy1) {
                    size_t rb = (pixBase + (size_t)(y0 + 1) * Wl) * 256 + t;
                    if (vx0) v10 = bf2f(V[rb + (size_t)x0 * 256]);
                    if (vx1) v11 = bf2f(V[rb + (size_t)x0 * 256 + 256]);
                }
                acc += a * (wy0 * (wx0 * v00 + wx1 * v01) + wy1 * (wx0 * v10 + wx1 * v11));
            }
            av[j] = acc;
        }
#pragma unroll
        for (int j = 0; j < 4; j++) att[j][t] = av[j];
    }
    __syncthreads();

    // output projection GEMV
    float au[4];
    {
        float bo = b_out[t];
#pragma unroll
        for (int j = 0; j < 4; j++) au[j] = bo;
    }
#pragma unroll 4
    for (int k = 0; k < 256; k++) {
        float w = W_out[k * 256 + t];
#pragma unroll
        for (int j = 0; j < 4; j++) au[j] += att[j][k] * w;
    }
#pragma unroll
    for (int j = 0; j < 4; j++)
        out[((size_t)b * LQ + q0 + j) * 256 + t] = au[j];
}

// ----------------------------------------------------------------
extern "C" void kernel_launch(void* const* d_in, const int* in_sizes, int n_in,
                              void* d_out, int out_size, void* d_ws, size_t ws_size,
                              hipStream_t stream) {
    const float* query   = (const float*)d_in[0];
    const float* refp    = (const float*)d_in[1];
    const float* value   = (const float*)d_in[2];
    const float* W_value = (const float*)d_in[3];
    const float* b_value = (const float*)d_in[4];
    const float* W_off   = (const float*)d_in[5];
    const float* b_off   = (const float*)d_in[6];
    const float* W_attn  = (const float*)d_in[7];
    const float* b_attn  = (const float*)d_in[8];
    const float* W_out   = (const float*)d_in[9];
    const float* b_out   = (const float*)d_in[10];
    float* out = (float*)d_out;

    unsigned short* Wt = (unsigned short*)d_ws;          // 256*256 bf16 = 128 KiB
    unsigned short* V  = Wt + 256 * 256;                 // 174080*256 bf16 = 89.1 MB

    k_wt<<<256, 256, 0, stream>>>(W_value, Wt);
    k_vproj<<<1360, 512, 0, stream>>>(value, Wt, b_value, V);
    k_attn<<<600, 256, 0, stream>>>(query, refp, W_off, b_off, W_attn, b_attn,
                                    W_out, b_out, V, out);
}

// Round 2
// 185.965 us; speedup vs baseline: 2.5177x; 2.5177x over previous
//
#include <hip/hip_runtime.h>

typedef short bf16x8 __attribute__((ext_vector_type(8)));
typedef unsigned short u16x8 __attribute__((ext_vector_type(8)));
typedef float f32x4 __attribute__((ext_vector_type(4)));

#define LQ 300
#define LV 21760
#define NQ 2400   // bs * LQ

__device__ __forceinline__ unsigned short f2bf(float x) {
    unsigned u = __float_as_uint(x);
    u += 0x7fff + ((u >> 16) & 1);   // round-to-nearest-even
    return (unsigned short)(u >> 16);
}
__device__ __forceinline__ float bf2f(unsigned short s) {
    return __uint_as_float(((unsigned)s) << 16);
}

// ---------------------------------------------------------------- K1: transpose+convert all weights to bf16 [n][k]
// Wt_v: 256x256, Wt_oa: 384x256 ([W_off | W_attn] cols), Wt_out: 256x256
__global__ void k_wt(const float* __restrict__ Wv, const float* __restrict__ Woff,
                     const float* __restrict__ Wattn, const float* __restrict__ Wout,
                     unsigned short* __restrict__ ws) {
    int i = blockIdx.x * 256 + threadIdx.x;   // 229376 total
    if (i < 65536) {
        int n = i >> 8, k = i & 255;
        ws[i] = f2bf(Wv[k * 256 + n]);
    } else if (i < 65536 + 98304) {
        int j = i - 65536;
        int n = j >> 8, k = j & 255;
        float s = (n < 256) ? Woff[k * 256 + n] : Wattn[k * 128 + (n - 256)];
        ws[i] = f2bf(s);
    } else {
        int j = i - 163840;
        int n = j >> 8, k = j & 255;
        ws[i] = f2bf(Wout[k * 256 + n]);
    }
}

// ---------------------------------------------------------------- K2: v = value @ W_value + b  (M=174080,N=256,K=256)
__global__ __launch_bounds__(512) void k_vproj(
    const float* __restrict__ A, const unsigned short* __restrict__ Bt,
    const float* __restrict__ bias, unsigned short* __restrict__ C)
{
    __shared__ unsigned short Alds[128][40];
    const int t = threadIdx.x;
    const int lane = t & 63;
    const int wid = t >> 6;
    const int wr = wid >> 2, wc = wid & 3;
    const size_t rowBase = (size_t)blockIdx.x * 128;

    const int srow = t >> 2, skh = (t & 3) * 8;
    const float* aptr = A + (rowBase + srow) * 256 + skh;

    const int fr = lane & 15;
    const int kg = lane >> 4;

    f32x4 acc[4][4];
#pragma unroll
    for (int m = 0; m < 4; m++)
#pragma unroll
        for (int n = 0; n < 4; n++) { f32x4 z = {0.f, 0.f, 0.f, 0.f}; acc[m][n] = z; }

    float4 f0 = *(const float4*)(aptr);
    float4 f1 = *(const float4*)(aptr + 4);

    for (int kk = 0; kk < 8; ++kk) {
        u16x8 pk;
        pk[0] = f2bf(f0.x); pk[1] = f2bf(f0.y); pk[2] = f2bf(f0.z); pk[3] = f2bf(f0.w);
        pk[4] = f2bf(f1.x); pk[5] = f2bf(f1.y); pk[6] = f2bf(f1.z); pk[7] = f2bf(f1.w);
        *(u16x8*)&Alds[srow][skh] = pk;
        __syncthreads();

        if (kk < 7) {   // prefetch next A chunk; completes under MFMA
            f0 = *(const float4*)(aptr + (kk + 1) * 32);
            f1 = *(const float4*)(aptr + (kk + 1) * 32 + 4);
        }

        bf16x8 a[4], bb[4];
#pragma unroll
        for (int m = 0; m < 4; m++)
            a[m] = *(const bf16x8*)&Alds[wr * 64 + m * 16 + fr][kg * 8];
#pragma unroll
        for (int n = 0; n < 4; n++)
            bb[n] = *(const bf16x8*)(Bt + (size_t)(wc * 64 + n * 16 + fr) * 256 + kk * 32 + kg * 8);
#pragma unroll
        for (int m = 0; m < 4; m++)
#pragma unroll
            for (int n = 0; n < 4; n++)
                acc[m][n] = __builtin_amdgcn_mfma_f32_16x16x32_bf16(a[m], bb[n], acc[m][n], 0, 0, 0);
        __syncthreads();
    }

#pragma unroll
    for (int m = 0; m < 4; m++) {
#pragma unroll
        for (int n = 0; n < 4; n++) {
            int col = wc * 64 + n * 16 + fr;
            float bv = bias[col];
#pragma unroll
            for (int r = 0; r < 4; r++) {
                size_t row = rowBase + wr * 64 + m * 16 + kg * 4 + r;
                C[row * 256 + col] = f2bf(acc[m][n][r] + bv);
            }
        }
    }
}

// ---------------------------------------------------------------- K3: [off|attn] = query @ [W_off|W_attn] + bias
// M=2400 (64/block), N=384, K=256. 8 waves: wr{0,1}x32 rows, wc{0..3}x96 cols. No LDS (query is L2-hot).
__global__ __launch_bounds__(512) void k_qproj(
    const float* __restrict__ Q, const unsigned short* __restrict__ Woa,
    const float* __restrict__ b_off, const float* __restrict__ b_attn,
    float* __restrict__ offattn)
{
    const int t = threadIdx.x;
    const int lane = t & 63;
    const int wid = t >> 6;
    const int wr = wid >> 2, wc = wid & 3;
    const int fr = lane & 15, kg = lane >> 4;
    const int rowBase = blockIdx.x * 64;

    const int r0 = min(rowBase + wr * 32 + fr, NQ - 1);
    const int r1 = min(rowBase + wr * 32 + 16 + fr, NQ - 1);

    f32x4 acc[2][6];
#pragma unroll
    for (int m = 0; m < 2; m++)
#pragma unroll
        for (int n = 0; n < 6; n++) { f32x4 z = {0.f, 0.f, 0.f, 0.f}; acc[m][n] = z; }

#pragma unroll
    for (int kk = 0; kk < 8; ++kk) {
        const int kb = kk * 32 + kg * 8;
        float4 q00 = *(const float4*)(Q + (size_t)r0 * 256 + kb);
        float4 q01 = *(const float4*)(Q + (size_t)r0 * 256 + kb + 4);
        float4 q10 = *(const float4*)(Q + (size_t)r1 * 256 + kb);
        float4 q11 = *(const float4*)(Q + (size_t)r1 * 256 + kb + 4);
        u16x8 a0, a1;
        a0[0] = f2bf(q00.x); a0[1] = f2bf(q00.y); a0[2] = f2bf(q00.z); a0[3] = f2bf(q00.w);
        a0[4] = f2bf(q01.x); a0[5] = f2bf(q01.y); a0[6] = f2bf(q01.z); a0[7] = f2bf(q01.w);
        a1[0] = f2bf(q10.x); a1[1] = f2bf(q10.y); a1[2] = f2bf(q10.z); a1[3] = f2bf(q10.w);
        a1[4] = f2bf(q11.x); a1[5] = f2bf(q11.y); a1[6] = f2bf(q11.z); a1[7] = f2bf(q11.w);
#pragma unroll
        for (int n = 0; n < 6; n++) {
            bf16x8 bb = *(const bf16x8*)(Woa + (size_t)(wc * 96 + n * 16 + fr) * 256 + kb);
            acc[0][n] = __builtin_amdgcn_mfma_f32_16x16x32_bf16((bf16x8)a0, bb, acc[0][n], 0, 0, 0);
            acc[1][n] = __builtin_amdgcn_mfma_f32_16x16x32_bf16((bf16x8)a1, bb, acc[1][n], 0, 0, 0);
        }
    }

#pragma unroll
    for (int m = 0; m < 2; m++) {
#pragma unroll
        for (int n = 0; n < 6; n++) {
            int col = wc * 96 + n * 16 + fr;
            float bv = (col < 256) ? b_off[col] : b_attn[col - 256];
#pragma unroll
            for (int r = 0; r < 4; r++) {
                int row = rowBase + wr * 32 + m * 16 + kg * 4 + r;
                if (row < NQ) offattn[(size_t)row * 384 + col] = acc[m][n][r] + bv;
            }
        }
    }
}

// ---------------------------------------------------------------- K4: softmax + grid + bilinear gather. 1 block = 1 query.
__global__ __launch_bounds__(256) void k_sample(
    const float* __restrict__ refp, const float* __restrict__ offattn,
    const unsigned short* __restrict__ V, unsigned short* __restrict__ att)
{
    __shared__ float aw[128], gx[128], gy[128];
    const int t = threadIdx.x;
    const int row = blockIdx.x;          // global query index
    const int b = row / LQ;
    const float* oa = offattn + (size_t)row * 384;

    if (t < 128) {
        // per-head softmax over 16 points (heads are 16-aligned within each wave)
        float logit = oa[256 + t];
        float m = logit;
        m = fmaxf(m, __shfl_xor(m, 1));
        m = fmaxf(m, __shfl_xor(m, 2));
        m = fmaxf(m, __shfl_xor(m, 4));
        m = fmaxf(m, __shfl_xor(m, 8));
        float e = __expf(logit - m);
        float s = e;
        s += __shfl_xor(s, 1);
        s += __shfl_xor(s, 2);
        s += __shfl_xor(s, 4);
        s += __shfl_xor(s, 8);
        aw[t] = e / s;
        // sampling location for point t (l = (t>>2)&3)
        const int l = (t >> 2) & 3;
        const float Wl = (l == 0) ? 128.f : (l == 1) ? 64.f : (l == 2) ? 32.f : 16.f;
        float ox = oa[2 * t], oy = oa[2 * t + 1];
        const float* rp = refp + ((size_t)row * 4 + l) * 4;
        gx[t] = (rp[0] + ox * 0.125f * rp[2]) * Wl - 0.5f;
        gy[t] = (rp[1] + oy * 0.125f * rp[3]) * Wl - 0.5f;
    }
    __syncthreads();

    const int h = t >> 5;
    float acc = 0.f;
#pragma unroll 4
    for (int jj = 0; jj < 16; jj++) {
        const int l = jj >> 2;
        const int Wl = (l == 0) ? 128 : (l == 1) ? 64 : (l == 2) ? 32 : 16;
        const int S  = (l == 0) ? 0 : (l == 1) ? 16384 : (l == 2) ? 20480 : 21504;
        int pt = h * 16 + jj;
        float a  = aw[pt];
        float sx = gx[pt], sy = gy[pt];
        float x0f = floorf(sx), y0f = floorf(sy);
        int   x0 = (int)x0f, y0 = (int)y0f;
        float wx1 = sx - x0f, wy1 = sy - y0f;
        float wx0 = 1.f - wx1, wy0 = 1.f - wy1;
        bool vx0 = (unsigned)x0 < (unsigned)Wl;
        bool vx1 = (unsigned)(x0 + 1) < (unsigned)Wl;
        bool vy0 = (unsigned)y0 < (unsigned)Wl;
        bool vy1 = (unsigned)(y0 + 1) < (unsigned)Wl;
        float v00 = 0.f, v01 = 0.f, v10 = 0.f, v11 = 0.f;
        size_t pixBase = (size_t)b * LV + S;
        if (vy0) {
            size_t rb = (pixBase + (size_t)y0 * Wl) * 256 + t;
            if (vx0) v00 = bf2f(V[rb + (size_t)x0 * 256]);
            if (vx1) v01 = bf2f(V[rb + (size_t)x0 * 256 + 256]);
        }
        if (vy1) {
            size_t rb = (pixBase + (size_t)(y0 + 1) * Wl) * 256 + t;
            if (vx0) v10 = bf2f(V[rb + (size_t)x0 * 256]);
            if (vx1) v11 = bf2f(V[rb + (size_t)x0 * 256 + 256]);
        }
        acc += a * (wy0 * (wx0 * v00 + wx1 * v01) + wy1 * (wx0 * v10 + wx1 * v11));
    }
    att[(size_t)row * 256 + t] = f2bf(acc);
}

// ---------------------------------------------------------------- K5: out = att @ W_out + b_out (M=2400,N=256,K=256)
__global__ __launch_bounds__(256) void k_outproj(
    const unsigned short* __restrict__ att, const unsigned short* __restrict__ Wout,
    const float* __restrict__ b_out, float* __restrict__ out)
{
    const int t = threadIdx.x;
    const int lane = t & 63;
    const int wc = t >> 6;
    const int fr = lane & 15, kg = lane >> 4;
    const int rowBase = blockIdx.x * 64;

    f32x4 acc[4][4];
#pragma unroll
    for (int m = 0; m < 4; m++)
#pragma unroll
        for (int n = 0; n < 4; n++) { f32x4 z = {0.f, 0.f, 0.f, 0.f}; acc[m][n] = z; }

#pragma unroll
    for (int kk = 0; kk < 8; ++kk) {
        const int kb = kk * 32 + kg * 8;
        bf16x8 a[4], bb[4];
#pragma unroll
        for (int m = 0; m < 4; m++) {
            int row = min(rowBase + m * 16 + fr, NQ - 1);
            a[m] = *(const bf16x8*)(att + (size_t)row * 256 + kb);
        }
#pragma unroll
        for (int n = 0; n < 4; n++)
            bb[n] = *(const bf16x8*)(Wout + (size_t)(wc * 64 + n * 16 + fr) * 256 + kb);
#pragma unroll
        for (int m = 0; m < 4; m++)
#pragma unroll
            for (int n = 0; n < 4; n++)
                acc[m][n] = __builtin_amdgcn_mfma_f32_16x16x32_bf16(a[m], bb[n], acc[m][n], 0, 0, 0);
    }

#pragma unroll
    for (int m = 0; m < 4; m++) {
#pragma unroll
        for (int n = 0; n < 4; n++) {
            int col = wc * 64 + n * 16 + fr;
            float bv = b_out[col];
#pragma unroll
            for (int r = 0; r < 4; r++) {
                int row = rowBase + m * 16 + kg * 4 + r;
                if (row < NQ) out[(size_t)row * 256 + col] = acc[m][n][r] + bv;
            }
        }
    }
}

// ----------------------------------------------------------------
extern "C" void kernel_launch(void* const* d_in, const int* in_sizes, int n_in,
                              void* d_out, int out_size, void* d_ws, size_t ws_size,
                              hipStream_t stream) {
    const float* query   = (const float*)d_in[0];
    const float* refp    = (const float*)d_in[1];
    const float* value   = (const float*)d_in[2];
    const float* W_value = (const float*)d_in[3];
    const float* b_value = (const float*)d_in[4];
    const float* W_off   = (const float*)d_in[5];
    const float* b_off   = (const float*)d_in[6];
    const float* W_attn  = (const float*)d_in[7];
    const float* b_attn  = (const float*)d_in[8];
    const float* W_out   = (const float*)d_in[9];
    const float* b_out   = (const float*)d_in[10];
    float* out = (float*)d_out;

    unsigned short* wsu   = (unsigned short*)d_ws;
    unsigned short* Wt_v  = wsu;                       // 65536
    unsigned short* Wt_oa = Wt_v + 65536;              // 98304
    unsigned short* Wt_out= Wt_oa + 98304;             // 65536
    unsigned short* V     = Wt_out + 65536;            // 174080*256
    float* offattn = (float*)(V + (size_t)174080 * 256);   // 2400*384 f32
    unsigned short* att = (unsigned short*)(offattn + (size_t)NQ * 384); // 2400*256 bf16

    k_wt<<<896, 256, 0, stream>>>(W_value, W_off, W_attn, W_out, wsu);
    k_qproj<<<38, 512, 0, stream>>>(query, Wt_oa, b_off, b_attn, offattn);
    k_vproj<<<1360, 512, 0, stream>>>(value, Wt_v, b_value, V);
    k_sample<<<NQ, 256, 0, stream>>>(refp, offattn, V, att);
    k_outproj<<<38, 256, 0, stream>>>(att, Wt_out, b_out, out);
}

// Round 3
// 171.855 us; speedup vs baseline: 2.7244x; 1.0821x over previous
//
#include <hip/hip_runtime.h>

typedef short bf16x8 __attribute__((ext_vector_type(8)));
typedef unsigned short u16x8 __attribute__((ext_vector_type(8)));
typedef float f32x4 __attribute__((ext_vector_type(4)));

#define LQ 300
#define LV 21760
#define NQ 2400   // bs * LQ

__device__ __forceinline__ unsigned short f2bf(float x) {
    unsigned u = __float_as_uint(x);
    u += 0x7fff + ((u >> 16) & 1);   // round-to-nearest-even
    return (unsigned short)(u >> 16);
}
__device__ __forceinline__ float bf2f(unsigned short s) {
    return __uint_as_float(((unsigned)s) << 16);
}

// ---------------------------------------------------------------- K1: transpose+convert all weights to bf16 [n][k]
__global__ void k_wt(const float* __restrict__ Wv, const float* __restrict__ Woff,
                     const float* __restrict__ Wattn, const float* __restrict__ Wout,
                     unsigned short* __restrict__ ws) {
    int i = blockIdx.x * 256 + threadIdx.x;   // 229376 total
    if (i < 65536) {
        int n = i >> 8, k = i & 255;
        ws[i] = f2bf(Wv[k * 256 + n]);
    } else if (i < 65536 + 98304) {
        int j = i - 65536;
        int n = j >> 8, k = j & 255;
        float s = (n < 256) ? Woff[k * 256 + n] : Wattn[k * 128 + (n - 256)];
        ws[i] = f2bf(s);
    } else {
        int j = i - 163840;
        int n = j >> 8, k = j & 255;
        ws[i] = f2bf(Wout[k * 256 + n]);
    }
}

// ---------------------------------------------------------------- K2: v = value @ W_value + b  (M=174080,N=256,K=256)
// One-shot LDS staging of the whole 128x256 A-tile, then a barrier-free MFMA loop,
// then coalesced C write via LDS round-trip. 512 thr = 8 waves (2x4), 64x64/wave.
__global__ __launch_bounds__(512, 4) void k_vproj(
    const float* __restrict__ A, const unsigned short* __restrict__ Bt,
    const float* __restrict__ bias, unsigned short* __restrict__ C)
{
    __shared__ unsigned short Alds[128][264];   // stride 264 u16 = 132 words ≡ 4 banks: 2-way (free)
    const int t = threadIdx.x;
    const int lane = t & 63;
    const int wid = t >> 6;
    const int wr = wid >> 2, wc = wid & 3;
    const size_t rowBase = (size_t)blockIdx.x * 128;
    const int fr = lane & 15, kg = lane >> 4;

    // ---- stage whole A tile: 32 B/lane/iter, fully coalesced, all loads in flight
    const float* abase = A + rowBase * 256;
#pragma unroll
    for (int i = 0; i < 8; i++) {
        int e = (i * 512 + t) * 8;          // flat element index in 128x256 tile
        int row = e >> 8, k = e & 255;
        float4 f0 = *(const float4*)(abase + e);
        float4 f1 = *(const float4*)(abase + e + 4);
        u16x8 pk;
        pk[0] = f2bf(f0.x); pk[1] = f2bf(f0.y); pk[2] = f2bf(f0.z); pk[3] = f2bf(f0.w);
        pk[4] = f2bf(f1.x); pk[5] = f2bf(f1.y); pk[6] = f2bf(f1.z); pk[7] = f2bf(f1.w);
        *(u16x8*)&Alds[row][k] = pk;
    }

    f32x4 acc[4][4];
#pragma unroll
    for (int m = 0; m < 4; m++)
#pragma unroll
        for (int n = 0; n < 4; n++) { f32x4 z = {0.f, 0.f, 0.f, 0.f}; acc[m][n] = z; }

    __syncthreads();

    // ---- barrier-free MFMA loop over K. B frags stream from L2-hot 128 KB Wt.
    for (int kk = 0; kk < 8; ++kk) {
        bf16x8 a[4], bb[4];
#pragma unroll
        for (int m = 0; m < 4; m++)
            a[m] = *(const bf16x8*)&Alds[wr * 64 + m * 16 + fr][kk * 32 + kg * 8];
#pragma unroll
        for (int n = 0; n < 4; n++)
            bb[n] = *(const bf16x8*)(Bt + (size_t)(wc * 64 + n * 16 + fr) * 256 + kk * 32 + kg * 8);
#pragma unroll
        for (int m = 0; m < 4; m++)
#pragma unroll
            for (int n = 0; n < 4; n++)
                acc[m][n] = __builtin_amdgcn_mfma_f32_16x16x32_bf16(a[m], bb[n], acc[m][n], 0, 0, 0);
    }

    // ---- epilogue: stage C tile (bf16) into LDS, then 16 B/lane coalesced stores
    __syncthreads();   // A reads complete before overwrite
#pragma unroll
    for (int n = 0; n < 4; n++) {
        int col = wc * 64 + n * 16 + fr;
        float bv = bias[col];
#pragma unroll
        for (int m = 0; m < 4; m++) {
#pragma unroll
            for (int r = 0; r < 4; r++)
                Alds[wr * 64 + m * 16 + kg * 4 + r][col] = f2bf(acc[m][n][r] + bv);
        }
    }
    __syncthreads();
    unsigned short* cbase = C + rowBase * 256;
#pragma unroll
    for (int i = 0; i < 8; i++) {
        int e = (i * 512 + t) * 8;
        int row = e >> 8, k = e & 255;
        *(u16x8*)(cbase + e) = *(const u16x8*)&Alds[row][k];
    }
}

// ---------------------------------------------------------------- K3: [off|attn] = query @ [W_off|W_attn] + bias
__global__ __launch_bounds__(512) void k_qproj(
    const float* __restrict__ Q, const unsigned short* __restrict__ Woa,
    const float* __restrict__ b_off, const float* __restrict__ b_attn,
    float* __restrict__ offattn)
{
    const int t = threadIdx.x;
    const int lane = t & 63;
    const int wid = t >> 6;
    const int wr = wid >> 2, wc = wid & 3;
    const int fr = lane & 15, kg = lane >> 4;
    const int rowBase = blockIdx.x * 64;

    const int r0 = min(rowBase + wr * 32 + fr, NQ - 1);
    const int r1 = min(rowBase + wr * 32 + 16 + fr, NQ - 1);

    f32x4 acc[2][6];
#pragma unroll
    for (int m = 0; m < 2; m++)
#pragma unroll
        for (int n = 0; n < 6; n++) { f32x4 z = {0.f, 0.f, 0.f, 0.f}; acc[m][n] = z; }

#pragma unroll
    for (int kk = 0; kk < 8; ++kk) {
        const int kb = kk * 32 + kg * 8;
        float4 q00 = *(const float4*)(Q + (size_t)r0 * 256 + kb);
        float4 q01 = *(const float4*)(Q + (size_t)r0 * 256 + kb + 4);
        float4 q10 = *(const float4*)(Q + (size_t)r1 * 256 + kb);
        float4 q11 = *(const float4*)(Q + (size_t)r1 * 256 + kb + 4);
        u16x8 a0, a1;
        a0[0] = f2bf(q00.x); a0[1] = f2bf(q00.y); a0[2] = f2bf(q00.z); a0[3] = f2bf(q00.w);
        a0[4] = f2bf(q01.x); a0[5] = f2bf(q01.y); a0[6] = f2bf(q01.z); a0[7] = f2bf(q01.w);
        a1[0] = f2bf(q10.x); a1[1] = f2bf(q10.y); a1[2] = f2bf(q10.z); a1[3] = f2bf(q10.w);
        a1[4] = f2bf(q11.x); a1[5] = f2bf(q11.y); a1[6] = f2bf(q11.z); a1[7] = f2bf(q11.w);
#pragma unroll
        for (int n = 0; n < 6; n++) {
            bf16x8 bb = *(const bf16x8*)(Woa + (size_t)(wc * 96 + n * 16 + fr) * 256 + kb);
            acc[0][n] = __builtin_amdgcn_mfma_f32_16x16x32_bf16((bf16x8)a0, bb, acc[0][n], 0, 0, 0);
            acc[1][n] = __builtin_amdgcn_mfma_f32_16x16x32_bf16((bf16x8)a1, bb, acc[1][n], 0, 0, 0);
        }
    }

#pragma unroll
    for (int m = 0; m < 2; m++) {
#pragma unroll
        for (int n = 0; n < 6; n++) {
            int col = wc * 96 + n * 16 + fr;
            float bv = (col < 256) ? b_off[col] : b_attn[col - 256];
#pragma unroll
            for (int r = 0; r < 4; r++) {
                int row = rowBase + wr * 32 + m * 16 + kg * 4 + r;
                if (row < NQ) offattn[(size_t)row * 384 + col] = acc[m][n][r] + bv;
            }
        }
    }
}

// ---------------------------------------------------------------- K4: softmax + grid + bilinear gather. 1 block = 1 query.
__global__ __launch_bounds__(256) void k_sample(
    const float* __restrict__ refp, const float* __restrict__ offattn,
    const unsigned short* __restrict__ V, unsigned short* __restrict__ att)
{
    __shared__ float aw[128], gx[128], gy[128];
    const int t = threadIdx.x;
    const int row = blockIdx.x;          // global query index
    const int b = row / LQ;
    const float* oa = offattn + (size_t)row * 384;

    if (t < 128) {
        float logit = oa[256 + t];
        float m = logit;
        m = fmaxf(m, __shfl_xor(m, 1));
        m = fmaxf(m, __shfl_xor(m, 2));
        m = fmaxf(m, __shfl_xor(m, 4));
        m = fmaxf(m, __shfl_xor(m, 8));
        float e = __expf(logit - m);
        float s = e;
        s += __shfl_xor(s, 1);
        s += __shfl_xor(s, 2);
        s += __shfl_xor(s, 4);
        s += __shfl_xor(s, 8);
        aw[t] = e / s;
        const int l = (t >> 2) & 3;
        const float Wl = (l == 0) ? 128.f : (l == 1) ? 64.f : (l == 2) ? 32.f : 16.f;
        float ox = oa[2 * t], oy = oa[2 * t + 1];
        const float* rp = refp + ((size_t)row * 4 + l) * 4;
        gx[t] = (rp[0] + ox * 0.125f * rp[2]) * Wl - 0.5f;
        gy[t] = (rp[1] + oy * 0.125f * rp[3]) * Wl - 0.5f;
    }
    __syncthreads();

    const int h = t >> 5;
    float acc = 0.f;
#pragma unroll 4
    for (int jj = 0; jj < 16; jj++) {
        const int l = jj >> 2;
        const int Wl = (l == 0) ? 128 : (l == 1) ? 64 : (l == 2) ? 32 : 16;
        const int S  = (l == 0) ? 0 : (l == 1) ? 16384 : (l == 2) ? 20480 : 21504;
        int pt = h * 16 + jj;
        float a  = aw[pt];
        float sx = gx[pt], sy = gy[pt];
        float x0f = floorf(sx), y0f = floorf(sy);
        int   x0 = (int)x0f, y0 = (int)y0f;
        float wx1 = sx - x0f, wy1 = sy - y0f;
        float wx0 = 1.f - wx1, wy0 = 1.f - wy1;
        bool vx0 = (unsigned)x0 < (unsigned)Wl;
        bool vx1 = (unsigned)(x0 + 1) < (unsigned)Wl;
        bool vy0 = (unsigned)y0 < (unsigned)Wl;
        bool vy1 = (unsigned)(y0 + 1) < (unsigned)Wl;
        float v00 = 0.f, v01 = 0.f, v10 = 0.f, v11 = 0.f;
        size_t pixBase = (size_t)b * LV + S;
        if (vy0) {
            size_t rb = (pixBase + (size_t)y0 * Wl) * 256 + t;
            if (vx0) v00 = bf2f(V[rb + (size_t)x0 * 256]);
            if (vx1) v01 = bf2f(V[rb + (size_t)x0 * 256 + 256]);
        }
        if (vy1) {
            size_t rb = (pixBase + (size_t)(y0 + 1) * Wl) * 256 + t;
            if (vx0) v10 = bf2f(V[rb + (size_t)x0 * 256]);
            if (vx1) v11 = bf2f(V[rb + (size_t)x0 * 256 + 256]);
        }
        acc += a * (wy0 * (wx0 * v00 + wx1 * v01) + wy1 * (wx0 * v10 + wx1 * v11));
    }
    att[(size_t)row * 256 + t] = f2bf(acc);
}

// ---------------------------------------------------------------- K5: out = att @ W_out + b_out (M=2400,N=256,K=256)
__global__ __launch_bounds__(256) void k_outproj(
    const unsigned short* __restrict__ att, const unsigned short* __restrict__ Wout,
    const float* __restrict__ b_out, float* __restrict__ out)
{
    const int t = threadIdx.x;
    const int lane = t & 63;
    const int wc = t >> 6;
    const int fr = lane & 15, kg = lane >> 4;
    const int rowBase = blockIdx.x * 64;

    f32x4 acc[4][4];
#pragma unroll
    for (int m = 0; m < 4; m++)
#pragma unroll
        for (int n = 0; n < 4; n++) { f32x4 z = {0.f, 0.f, 0.f, 0.f}; acc[m][n] = z; }

#pragma unroll
    for (int kk = 0; kk < 8; ++kk) {
        const int kb = kk * 32 + kg * 8;
        bf16x8 a[4], bb[4];
#pragma unroll
        for (int m = 0; m < 4; m++) {
            int row = min(rowBase + m * 16 + fr, NQ - 1);
            a[m] = *(const bf16x8*)(att + (size_t)row * 256 + kb);
        }
#pragma unroll
        for (int n = 0; n < 4; n++)
            bb[n] = *(const bf16x8*)(Wout + (size_t)(wc * 64 + n * 16 + fr) * 256 + kb);
#pragma unroll
        for (int m = 0; m < 4; m++)
#pragma unroll
            for (int n = 0; n < 4; n++)
                acc[m][n] = __builtin_amdgcn_mfma_f32_16x16x32_bf16(a[m], bb[n], acc[m][n], 0, 0, 0);
    }

#pragma unroll
    for (int m = 0; m < 4; m++) {
#pragma unroll
        for (int n = 0; n < 4; n++) {
            int col = wc * 64 + n * 16 + fr;
            float bv = b_out[col];
#pragma unroll
            for (int r = 0; r < 4; r++) {
                int row = rowBase + m * 16 + kg * 4 + r;
                if (row < NQ) out[(size_t)row * 256 + col] = acc[m][n][r] + bv;
            }
        }
    }
}

// ----------------------------------------------------------------
extern "C" void kernel_launch(void* const* d_in, const int* in_sizes, int n_in,
                              void* d_out, int out_size, void* d_ws, size_t ws_size,
                              hipStream_t stream) {
    const float* query   = (const float*)d_in[0];
    const float* refp    = (const float*)d_in[1];
    const float* value   = (const float*)d_in[2];
    const float* W_value = (const float*)d_in[3];
    const float* b_value = (const float*)d_in[4];
    const float* W_off   = (const float*)d_in[5];
    const float* b_off   = (const float*)d_in[6];
    const float* W_attn  = (const float*)d_in[7];
    const float* b_attn  = (const float*)d_in[8];
    const float* W_out   = (const float*)d_in[9];
    const float* b_out   = (const float*)d_in[10];
    float* out = (float*)d_out;

    unsigned short* wsu   = (unsigned short*)d_ws;
    unsigned short* Wt_v  = wsu;                       // 65536
    unsigned short* Wt_oa = Wt_v + 65536;              // 98304
    unsigned short* Wt_out= Wt_oa + 98304;             // 65536
    unsigned short* V     = Wt_out + 65536;            // 174080*256
    float* offattn = (float*)(V + (size_t)174080 * 256);   // 2400*384 f32
    unsigned short* att = (unsigned short*)(offattn + (size_t)NQ * 384); // 2400*256 bf16

    k_wt<<<896, 256, 0, stream>>>(W_value, W_off, W_attn, W_out, wsu);
    k_qproj<<<38, 512, 0, stream>>>(query, Wt_oa, b_off, b_attn, offattn);
    k_vproj<<<1360, 512, 0, stream>>>(value, Wt_v, b_value, V);
    k_sample<<<NQ, 256, 0, stream>>>(refp, offattn, V, att);
    k_outproj<<<38, 256, 0, stream>>>(att, Wt_out, b_out, out);
}